// Round 9
// baseline (228.421 us; speedup 1.0000x reference)
//
#include <hip/hip_runtime.h>
#include <hip/hip_bf16.h>
#include <stdint.h>

typedef unsigned short u16;
typedef uint32_t u32;
typedef short s16x8 __attribute__((ext_vector_type(8)));
typedef float f32x4 __attribute__((ext_vector_type(4)));

#define SDIM 2048
#define EDIM 1024

static __device__ __forceinline__ float b2f(u16 v) {
    union { float f; u32 u; } c; c.u = ((u32)v) << 16; return c.f;
}
static __device__ __forceinline__ u16 f2b(float f) {
    union { float f; u32 u; } c; c.f = f;
    u32 u = c.u;
    u32 r = (u + 0x7FFFu + ((u >> 16) & 1u)) >> 16;
    return (u16)r;
}
static __device__ __forceinline__ void gll16(const u16* g, u16* l) {
    __builtin_amdgcn_global_load_lds(
        (const __attribute__((address_space(1))) void*)g,
        (__attribute__((address_space(3))) void*)l, 16, 0, 0);
}

// per-wave dtype sniff (verified R1/R5)
static __device__ __forceinline__ int sniff_bf16(const u16* __restrict__ x) {
    u16 v = x[(threadIdx.x & 63) * 2];
    int e = (v >> 7) & 0xFF;
    unsigned long long m = __ballot(e >= 90 && e <= 144);
    return __popcll(m) >= 48;
}

// ---- fused prep: z=0 Wa^T, z=1 Wp^T (LDS-tiled), z=2 X convert (fp32 path) ----
__global__ __launch_bounds__(256) void k_prep(
    const void* __restrict__ X, const void* __restrict__ Wa,
    const void* __restrict__ Wp, u16* __restrict__ Xb,
    u16* __restrict__ WtA, u16* __restrict__ WtP) {
    int f = sniff_bf16((const u16*)X);
    int z = blockIdx.z;
    int t = threadIdx.x;
    if (z == 2) {
        if (f) return;
        const float* s = (const float*)X;
        int bid = blockIdx.y * 48 + blockIdx.x;
        for (int c = bid; c < 2048; c += 768) {
            long i = ((long)c * 256 + t) * 8;
            u16 o[8];
            for (int j = 0; j < 8; ++j) o[j] = f2b(s[i + j]);
            *(uint4*)&Xb[i] = *(uint4*)o;
        }
        return;
    }
    if (z == 1 && blockIdx.x >= 16) return;
    const void* src = z ? Wp : Wa;
    u16* dst = z ? WtP : WtA;
    int Nsrc = z ? 1024 : 3072;
    int n0 = blockIdx.x * 64, k0 = blockIdx.y * 64;
    __shared__ u16 L[64 * 72];
    int r = t >> 2, c0 = (t & 3) * 16;
    u16 val[16];
    if (f) {
        const u16* s = (const u16*)src + (size_t)(k0 + r) * Nsrc + n0 + c0;
        *(uint4*)&val[0] = *(const uint4*)s;
        *(uint4*)&val[8] = *(const uint4*)(s + 8);
    } else {
        const float* s = (const float*)src + (size_t)(k0 + r) * Nsrc + n0 + c0;
        for (int j = 0; j < 16; ++j) val[j] = f2b(s[j]);
    }
    for (int j = 0; j < 16; ++j) L[(c0 + j) * 72 + r] = val[j];
    __syncthreads();
    uint4 o0 = *(const uint4*)&L[r * 72 + c0];
    uint4 o1 = *(const uint4*)&L[r * 72 + c0 + 8];
    u16* d = dst + (size_t)(n0 + r) * 1024 + k0 + c0;
    *(uint4*)d = o0;
    *(uint4*)(d + 8) = o1;
}

// ---- GEMM1: QKV = X @ WtA^T + b. 128x128, BK=32, single-barrier LDS dbuf.
// Prefetch for iter n+1 issues at start of iter n -> DMA has the whole compute
// phase in flight before the end-of-iter barrier's vmcnt(0) drain.
// Epilogue scatters to head-major QKVh[kind][b][h][s][d].
__global__ __launch_bounds__(256) void k_gemm1(
    const u16* __restrict__ Xraw, const u16* __restrict__ Xb,
    const u16* __restrict__ Bt, const void* __restrict__ bias,
    u16* __restrict__ C) {
    const int K = 1024;
    __shared__ u16 As[2][4096];      // 2 x (128 rows x 32 k) = 16 KB
    __shared__ u16 Bs[2][4096];
    int f = sniff_bf16(Xraw);
    const u16* A = f ? Xraw : Xb;
    int t = threadIdx.x, wave = t >> 6, lane = t & 63;
    int m0 = blockIdx.y * 128, n0 = blockIdx.x * 128;
    int wm = (wave >> 1) * 64, wn = (wave & 1) * 64;
    int lm = lane & 15, lk = (lane >> 4) * 8;
    int sr = t >> 2, sc = (t & 3) * 8;
    const u16* Ap = A + (size_t)(m0 + sr) * K + sc;
    const u16* Bp = Bt + (size_t)(n0 + sr) * K + sc;
    int wo = wave * 512;

    f32x4 acc[4][4];
    f32x4 z = {0.f, 0.f, 0.f, 0.f};
    for (int mi = 0; mi < 4; ++mi)
        for (int ni = 0; ni < 4; ++ni) acc[mi][ni] = z;

    // prologue: stage k-chunk 0 into buf0
    gll16(Ap, &As[0][wo]);
    gll16(Ap + (size_t)64 * K, &As[0][wo + 2048]);
    gll16(Bp, &Bs[0][wo]);
    gll16(Bp + (size_t)64 * K, &Bs[0][wo + 2048]);
    __syncthreads();

    for (int it = 0; it < 32; ++it) {
        int cur = it & 1;
        if (it < 31) {                       // prefetch next chunk into other buf
            int kn = (it + 1) * 32;
            gll16(Ap + kn, &As[cur ^ 1][wo]);
            gll16(Ap + (size_t)64 * K + kn, &As[cur ^ 1][wo + 2048]);
            gll16(Bp + kn, &Bs[cur ^ 1][wo]);
            gll16(Bp + (size_t)64 * K + kn, &Bs[cur ^ 1][wo + 2048]);
        }
        s16x8 af[4], bfr[4];
        for (int mi = 0; mi < 4; ++mi)
            af[mi] = *(const s16x8*)&As[cur][(wm + mi * 16 + lm) * 32 + lk];
        for (int ni = 0; ni < 4; ++ni)
            bfr[ni] = *(const s16x8*)&Bs[cur][(wn + ni * 16 + lm) * 32 + lk];
        for (int mi = 0; mi < 4; ++mi)
            for (int ni = 0; ni < 4; ++ni)
                acc[mi][ni] = __builtin_amdgcn_mfma_f32_16x16x32_bf16(
                    af[mi], bfr[ni], acc[mi][ni], 0, 0, 0);
        __syncthreads();                     // single barrier: drains ds + prefetch
    }

    int cn = lane & 15, cr = (lane >> 4) * 4;
    for (int ni = 0; ni < 4; ++ni) {
        int gn = n0 + wn + ni * 16 + cn;
        float bb = f ? b2f(((const u16*)bias)[gn]) : ((const float*)bias)[gn];
        int kind = gn >> 10, rem = gn & 1023;
        int h = rem >> 6, d = rem & 63;
        int hm = kind * 32 + h;
        for (int mi = 0; mi < 4; ++mi)
            for (int r = 0; r < 4; ++r) {
                int gm = m0 + wm + mi * 16 + cr + r;
                int b = gm >> 11, s = gm & 2047;
                size_t o = ((size_t)((hm + b * 16) * 2048 + s)) * 64 + d;
                C[o] = f2b(acc[mi][ni][r] + bb);
            }
    }
}

// ---- GEMM2: out = AO @ WtP^T + b. 64x128, BK=32, single-barrier LDS dbuf ----
__global__ __launch_bounds__(256) void k_gemm2(
    const u16* __restrict__ Xraw, const u16* __restrict__ A,
    const u16* __restrict__ Bt, const void* __restrict__ bias,
    u16* __restrict__ Cb, float* __restrict__ Cf) {
    const int K = 1024, N = 1024;
    __shared__ u16 As[2][2048];      // 2 x (64 x 32) = 8 KB
    __shared__ u16 Bs[2][4096];      // 2 x (128 x 32) = 16 KB
    int f = sniff_bf16(Xraw);
    int t = threadIdx.x, wave = t >> 6, lane = t & 63;
    int m0 = blockIdx.y * 64, n0 = blockIdx.x * 128;
    int wm = (wave >> 1) * 32, wn = (wave & 1) * 64;
    int lm = lane & 15, lk = (lane >> 4) * 8;
    int sr = t >> 2, sc = (t & 3) * 8;
    const u16* Ap = A + (size_t)(m0 + sr) * K + sc;
    const u16* Bp = Bt + (size_t)(n0 + sr) * K + sc;
    int wo = wave * 512;

    f32x4 acc[2][4];
    f32x4 z = {0.f, 0.f, 0.f, 0.f};
    for (int mi = 0; mi < 2; ++mi)
        for (int ni = 0; ni < 4; ++ni) acc[mi][ni] = z;

    gll16(Ap, &As[0][wo]);
    gll16(Bp, &Bs[0][wo]);
    gll16(Bp + (size_t)64 * K, &Bs[0][wo + 2048]);
    __syncthreads();

    for (int it = 0; it < 32; ++it) {
        int cur = it & 1;
        if (it < 31) {
            int kn = (it + 1) * 32;
            gll16(Ap + kn, &As[cur ^ 1][wo]);
            gll16(Bp + kn, &Bs[cur ^ 1][wo]);
            gll16(Bp + (size_t)64 * K + kn, &Bs[cur ^ 1][wo + 2048]);
        }
        s16x8 af[2], bfr[4];
        for (int mi = 0; mi < 2; ++mi)
            af[mi] = *(const s16x8*)&As[cur][(wm + mi * 16 + lm) * 32 + lk];
        for (int ni = 0; ni < 4; ++ni)
            bfr[ni] = *(const s16x8*)&Bs[cur][(wn + ni * 16 + lm) * 32 + lk];
        for (int mi = 0; mi < 2; ++mi)
            for (int ni = 0; ni < 4; ++ni)
                acc[mi][ni] = __builtin_amdgcn_mfma_f32_16x16x32_bf16(
                    af[mi], bfr[ni], acc[mi][ni], 0, 0, 0);
        __syncthreads();
    }

    int store_f32 = (f == 0);
    int cn = lane & 15, cr = (lane >> 4) * 4;
    for (int ni = 0; ni < 4; ++ni) {
        int gn = n0 + wn + ni * 16 + cn;
        float bb = f ? b2f(((const u16*)bias)[gn]) : ((const float*)bias)[gn];
        for (int mi = 0; mi < 2; ++mi)
            for (int r = 0; r < 4; ++r) {
                int gm = m0 + wm + mi * 16 + cr + r;
                float v = acc[mi][ni][r] + bb;
                size_t o = (size_t)gm * N + gn;
                if (store_f32) Cf[o] = v;
                else           Cb[o] = f2b(v);
            }
    }
}

// ---- MFMA sparse attention, head-major input, dynamic key-tile count ----
#define VP 264
#define PP 264
__global__ __launch_bounds__(256) void k_attn5(const u16* __restrict__ QKV,
                                               u16* __restrict__ AO) {
    int bx = blockIdx.x, h = blockIdx.y, b = blockIdx.z;
    int qb = bx >> 1, sb = bx & 1;
    int t = threadIdx.x, lane = t & 63, wave = t >> 6;
    int lm = lane & 15, q4 = lane >> 4;
    int nstr = qb << 3;
    int nk = nstr + (sb << 6) + 64;        // <= 248
    int kmax = (nk + 31) & ~31;            // padded key count, multiple of 32
    int ntile = kmax >> 4;                 // # of 16-wide key tiles (even)
    int r0 = (qb << 7) + (sb << 6);

    __shared__ char smem[79872];
    u16* Vts = (u16*)smem;                       // 64 x 264
    u16* Qs  = (u16*)(smem + 33792);             // 64 x 72
    u16* Ks  = (u16*)(smem + 33792 + 9216);      // 256 x 72
    u16* Ps  = (u16*)(smem + 33792);             // aliases Qs+Ks

    int hm = b * 16 + h;
    const u16* qp = QKV + ((size_t)hm * 2048 + r0) * 64;
    const u16* kp = QKV + ((size_t)(32 + hm) * 2048) * 64;
    const u16* vp = QKV + ((size_t)(64 + hm) * 2048) * 64;

    for (int c = t; c < 512; c += 256) {
        int r = c >> 3, d0 = (c & 7) << 3;
        *(uint4*)&Qs[r * 72 + d0] = *(const uint4*)(qp + c * 8);
    }
    uint4 zz = {0u, 0u, 0u, 0u};
    for (int c = t; c < (kmax << 3); c += 256) {
        int i = c >> 3, d0 = (c & 7) << 3;
        uint4 kv = zz;
        if (i < nk) {
            int key = (i < nstr) ? (((i >> 3) << 7) + 120 + (i & 7))
                                 : ((qb << 7) + (i - nstr));
            kv = *(const uint4*)(kp + key * 64 + d0);
        }
        *(uint4*)&Ks[i * 72 + d0] = kv;
    }
    {
        int i0 = (t & 31) * 8, d0 = (t >> 5) * 8;
        if (i0 < kmax) {
            u16 m8[8][8];
            for (int r = 0; r < 8; ++r) {
                int i = i0 + r;
                uint4 vv = zz;
                if (i < nk) {
                    int key = (i < nstr) ? (((i >> 3) << 7) + 120 + (i & 7))
                                         : ((qb << 7) + (i - nstr));
                    vv = *(const uint4*)(vp + key * 64 + d0);
                }
                *(uint4*)m8[r] = vv;
            }
            for (int j = 0; j < 8; ++j) {
                u16 o[8];
                for (int r = 0; r < 8; ++r) o[r] = m8[r][j];
                *(uint4*)&Vts[(d0 + j) * VP + i0] = *(uint4*)o;
            }
        }
    }
    __syncthreads();

    f32x4 acc[16];
    f32x4 z4 = {0.f, 0.f, 0.f, 0.f};
    for (int ni = 0; ni < 16; ++ni) acc[ni] = z4;
    s16x8 af0 = *(const s16x8*)&Qs[(wave * 16 + lm) * 72 + q4 * 8];
    s16x8 af1 = *(const s16x8*)&Qs[(wave * 16 + lm) * 72 + 32 + q4 * 8];
    for (int ni = 0; ni < ntile; ++ni) {
        s16x8 bf0 = *(const s16x8*)&Ks[(ni * 16 + lm) * 72 + q4 * 8];
        s16x8 bf1 = *(const s16x8*)&Ks[(ni * 16 + lm) * 72 + 32 + q4 * 8];
        acc[ni] = __builtin_amdgcn_mfma_f32_16x16x32_bf16(af0, bf0, acc[ni], 0, 0, 0);
        acc[ni] = __builtin_amdgcn_mfma_f32_16x16x32_bf16(af1, bf1, acc[ni], 0, 0, 0);
    }
    __syncthreads();

    float mx[4] = {-3e38f, -3e38f, -3e38f, -3e38f};
    for (int ni = 0; ni < ntile; ++ni) {
        int i = ni * 16 + lm;
        for (int reg = 0; reg < 4; ++reg) {
            int rl = (sb << 6) + wave * 16 + q4 * 4 + reg;
            bool valid = (i < nstr) || ((i - nstr) <= rl);
            float v = valid ? acc[ni][reg] * 0.125f : -3e38f;
            acc[ni][reg] = v;
            mx[reg] = fmaxf(mx[reg], v);
        }
    }
    for (int reg = 0; reg < 4; ++reg)
        for (int off = 1; off < 16; off <<= 1)
            mx[reg] = fmaxf(mx[reg], __shfl_xor(mx[reg], off, 64));
    float sm[4] = {0.f, 0.f, 0.f, 0.f};
    for (int ni = 0; ni < ntile; ++ni)
        for (int reg = 0; reg < 4; ++reg) {
            float e = __expf(acc[ni][reg] - mx[reg]);
            acc[ni][reg] = e;
            sm[reg] += e;
        }
    for (int reg = 0; reg < 4; ++reg)
        for (int off = 1; off < 16; off <<= 1)
            sm[reg] += __shfl_xor(sm[reg], off, 64);
    float inv[4];
    for (int reg = 0; reg < 4; ++reg) inv[reg] = 1.f / sm[reg];

    for (int ni = 0; ni < ntile; ++ni) {
        int i = ni * 16 + lm;
        for (int reg = 0; reg < 4; ++reg)
            Ps[(wave * 16 + q4 * 4 + reg) * PP + i] = f2b(acc[ni][reg]);
    }
    __syncthreads();

    f32x4 acc2[4];
    for (int ni2 = 0; ni2 < 4; ++ni2) acc2[ni2] = z4;
    for (int k0 = 0; k0 < kmax; k0 += 32) {
        s16x8 pf = *(const s16x8*)&Ps[(wave * 16 + lm) * PP + k0 + q4 * 8];
        for (int ni2 = 0; ni2 < 4; ++ni2) {
            s16x8 vf = *(const s16x8*)&Vts[(ni2 * 16 + lm) * VP + k0 + q4 * 8];
            acc2[ni2] = __builtin_amdgcn_mfma_f32_16x16x32_bf16(pf, vf, acc2[ni2], 0, 0, 0);
        }
    }
    int srow = r0 + wave * 16 + q4 * 4;
    for (int ni2 = 0; ni2 < 4; ++ni2)
        for (int reg = 0; reg < 4; ++reg) {
            size_t o = ((size_t)(b * SDIM + srow + reg)) * EDIM + h * 64 + ni2 * 16 + lm;
            AO[o] = f2b(acc2[ni2][reg] * inv[reg]);
        }
}

extern "C" void kernel_launch(void* const* d_in, const int* in_sizes, int n_in,
                              void* d_out, int out_size, void* d_ws, size_t ws_size,
                              hipStream_t stream) {
    const void* X  = d_in[0];
    const void* Wa = d_in[1];
    const void* ba = d_in[2];
    const void* Wp = d_in[3];
    const void* bp = d_in[4];

    char* w = (char*)d_ws;
    u16* Xb   = (u16*)(w);
    u16* WtA  = (u16*)(w + 8388608);
    u16* WtP  = (u16*)(w + 14680064);
    u16* QKVh = (u16*)(w + 16777216);
    u16* AO   = (u16*)(w + 41943040);

    k_prep<<<dim3(48, 16, 3), 256, 0, stream>>>(X, Wa, Wp, Xb, WtA, WtP);
    k_gemm1<<<dim3(24, 32), 256, 0, stream>>>((const u16*)X, Xb, WtA, ba, QKVh);
    k_attn5<<<dim3(32, 16, 2), 256, 0, stream>>>(QKVh, AO);
    k_gemm2<<<dim3(8, 64), 256, 0, stream>>>((const u16*)X, AO, WtP, bp,
                                             (u16*)d_out, (float*)d_out);
}

// Round 10
// 168.374 us; speedup vs baseline: 1.3566x; 1.3566x over previous
//
#include <hip/hip_runtime.h>
#include <hip/hip_bf16.h>
#include <stdint.h>

typedef unsigned short u16;
typedef uint32_t u32;
typedef short s16x8 __attribute__((ext_vector_type(8)));
typedef float f32x4 __attribute__((ext_vector_type(4)));

#define SDIM 2048
#define EDIM 1024

static __device__ __forceinline__ float b2f(u16 v) {
    union { float f; u32 u; } c; c.u = ((u32)v) << 16; return c.f;
}
static __device__ __forceinline__ u16 f2b(float f) {
    union { float f; u32 u; } c; c.f = f;
    u32 u = c.u;
    u32 r = (u + 0x7FFFu + ((u >> 16) & 1u)) >> 16;
    return (u16)r;
}
static __device__ __forceinline__ void gll16(const u16* g, u16* l) {
    __builtin_amdgcn_global_load_lds(
        (const __attribute__((address_space(1))) void*)g,
        (__attribute__((address_space(3))) void*)l, 16, 0, 0);
}

// per-wave dtype sniff (verified R1/R5)
static __device__ __forceinline__ int sniff_bf16(const u16* __restrict__ x) {
    u16 v = x[(threadIdx.x & 63) * 2];
    int e = (v >> 7) & 0xFF;
    unsigned long long m = __ballot(e >= 90 && e <= 144);
    return __popcll(m) >= 48;
}

// ---- fused prep: z=0 Wa^T, z=1 Wp^T (LDS-tiled), z=2 X convert (fp32 path) ----
__global__ __launch_bounds__(256) void k_prep(
    const void* __restrict__ X, const void* __restrict__ Wa,
    const void* __restrict__ Wp, u16* __restrict__ Xb,
    u16* __restrict__ WtA, u16* __restrict__ WtP) {
    int f = sniff_bf16((const u16*)X);
    int z = blockIdx.z;
    int t = threadIdx.x;
    if (z == 2) {
        if (f) return;
        const float* s = (const float*)X;
        int bid = blockIdx.y * 48 + blockIdx.x;
        for (int c = bid; c < 2048; c += 768) {
            long i = ((long)c * 256 + t) * 8;
            u16 o[8];
            for (int j = 0; j < 8; ++j) o[j] = f2b(s[i + j]);
            *(uint4*)&Xb[i] = *(uint4*)o;
        }
        return;
    }
    if (z == 1 && blockIdx.x >= 16) return;
    const void* src = z ? Wp : Wa;
    u16* dst = z ? WtP : WtA;
    int Nsrc = z ? 1024 : 3072;
    int n0 = blockIdx.x * 64, k0 = blockIdx.y * 64;
    __shared__ u16 L[64 * 72];
    int r = t >> 2, c0 = (t & 3) * 16;
    u16 val[16];
    if (f) {
        const u16* s = (const u16*)src + (size_t)(k0 + r) * Nsrc + n0 + c0;
        *(uint4*)&val[0] = *(const uint4*)s;
        *(uint4*)&val[8] = *(const uint4*)(s + 8);
    } else {
        const float* s = (const float*)src + (size_t)(k0 + r) * Nsrc + n0 + c0;
        for (int j = 0; j < 16; ++j) val[j] = f2b(s[j]);
    }
    for (int j = 0; j < 16; ++j) L[(c0 + j) * 72 + r] = val[j];
    __syncthreads();
    uint4 o0 = *(const uint4*)&L[r * 72 + c0];
    uint4 o1 = *(const uint4*)&L[r * 72 + c0 + 8];
    u16* d = dst + (size_t)(n0 + r) * 1024 + k0 + c0;
    *(uint4*)d = o0;
    *(uint4*)(d + 8) = o1;
}

// ---- GEMM1 (R9-proven dbuf): QKV = X @ WtA^T + b. 128x128, BK=32,
// single-barrier LDS double-buffer; head-major epilogue scatter ----
__global__ __launch_bounds__(256) void k_gemm1(
    const u16* __restrict__ Xraw, const u16* __restrict__ Xb,
    const u16* __restrict__ Bt, const void* __restrict__ bias,
    u16* __restrict__ C) {
    const int K = 1024;
    __shared__ u16 As[2][4096];
    __shared__ u16 Bs[2][4096];
    int f = sniff_bf16(Xraw);
    const u16* A = f ? Xraw : Xb;
    int t = threadIdx.x, wave = t >> 6, lane = t & 63;
    int m0 = blockIdx.y * 128, n0 = blockIdx.x * 128;
    int wm = (wave >> 1) * 64, wn = (wave & 1) * 64;
    int lm = lane & 15, lk = (lane >> 4) * 8;
    int sr = t >> 2, sc = (t & 3) * 8;
    const u16* Ap = A + (size_t)(m0 + sr) * K + sc;
    const u16* Bp = Bt + (size_t)(n0 + sr) * K + sc;
    int wo = wave * 512;

    f32x4 acc[4][4];
    f32x4 z = {0.f, 0.f, 0.f, 0.f};
    for (int mi = 0; mi < 4; ++mi)
        for (int ni = 0; ni < 4; ++ni) acc[mi][ni] = z;

    gll16(Ap, &As[0][wo]);
    gll16(Ap + (size_t)64 * K, &As[0][wo + 2048]);
    gll16(Bp, &Bs[0][wo]);
    gll16(Bp + (size_t)64 * K, &Bs[0][wo + 2048]);
    __syncthreads();

    for (int it = 0; it < 32; ++it) {
        int cur = it & 1;
        if (it < 31) {
            int kn = (it + 1) * 32;
            gll16(Ap + kn, &As[cur ^ 1][wo]);
            gll16(Ap + (size_t)64 * K + kn, &As[cur ^ 1][wo + 2048]);
            gll16(Bp + kn, &Bs[cur ^ 1][wo]);
            gll16(Bp + (size_t)64 * K + kn, &Bs[cur ^ 1][wo + 2048]);
        }
        s16x8 af[4], bfr[4];
        for (int mi = 0; mi < 4; ++mi)
            af[mi] = *(const s16x8*)&As[cur][(wm + mi * 16 + lm) * 32 + lk];
        for (int ni = 0; ni < 4; ++ni)
            bfr[ni] = *(const s16x8*)&Bs[cur][(wn + ni * 16 + lm) * 32 + lk];
        for (int mi = 0; mi < 4; ++mi)
            for (int ni = 0; ni < 4; ++ni)
                acc[mi][ni] = __builtin_amdgcn_mfma_f32_16x16x32_bf16(
                    af[mi], bfr[ni], acc[mi][ni], 0, 0, 0);
        __syncthreads();
    }

    int cn = lane & 15, cr = (lane >> 4) * 4;
    for (int ni = 0; ni < 4; ++ni) {
        int gn = n0 + wn + ni * 16 + cn;
        float bb = f ? b2f(((const u16*)bias)[gn]) : ((const float*)bias)[gn];
        int kind = gn >> 10, rem = gn & 1023;
        int h = rem >> 6, d = rem & 63;
        int hm = kind * 32 + h;
        for (int mi = 0; mi < 4; ++mi)
            for (int r = 0; r < 4; ++r) {
                int gm = m0 + wm + mi * 16 + cr + r;
                int b = gm >> 11, s = gm & 2047;
                size_t o = ((size_t)((hm + b * 16) * 2048 + s)) * 64 + d;
                C[o] = f2b(acc[mi][ni][r] + bb);
            }
    }
}

// ---- GEMM2 (R9-proven dbuf): out = AO @ WtP^T + b. 64x128, BK=32 ----
__global__ __launch_bounds__(256) void k_gemm2(
    const u16* __restrict__ Xraw, const u16* __restrict__ A,
    const u16* __restrict__ Bt, const void* __restrict__ bias,
    u16* __restrict__ Cb, float* __restrict__ Cf) {
    const int K = 1024, N = 1024;
    __shared__ u16 As[2][2048];
    __shared__ u16 Bs[2][4096];
    int f = sniff_bf16(Xraw);
    int t = threadIdx.x, wave = t >> 6, lane = t & 63;
    int m0 = blockIdx.y * 64, n0 = blockIdx.x * 128;
    int wm = (wave >> 1) * 32, wn = (wave & 1) * 64;
    int lm = lane & 15, lk = (lane >> 4) * 8;
    int sr = t >> 2, sc = (t & 3) * 8;
    const u16* Ap = A + (size_t)(m0 + sr) * K + sc;
    const u16* Bp = Bt + (size_t)(n0 + sr) * K + sc;
    int wo = wave * 512;

    f32x4 acc[2][4];
    f32x4 z = {0.f, 0.f, 0.f, 0.f};
    for (int mi = 0; mi < 2; ++mi)
        for (int ni = 0; ni < 4; ++ni) acc[mi][ni] = z;

    gll16(Ap, &As[0][wo]);
    gll16(Bp, &Bs[0][wo]);
    gll16(Bp + (size_t)64 * K, &Bs[0][wo + 2048]);
    __syncthreads();

    for (int it = 0; it < 32; ++it) {
        int cur = it & 1;
        if (it < 31) {
            int kn = (it + 1) * 32;
            gll16(Ap + kn, &As[cur ^ 1][wo]);
            gll16(Bp + kn, &Bs[cur ^ 1][wo]);
            gll16(Bp + (size_t)64 * K + kn, &Bs[cur ^ 1][wo + 2048]);
        }
        s16x8 af[2], bfr[4];
        for (int mi = 0; mi < 2; ++mi)
            af[mi] = *(const s16x8*)&As[cur][(wm + mi * 16 + lm) * 32 + lk];
        for (int ni = 0; ni < 4; ++ni)
            bfr[ni] = *(const s16x8*)&Bs[cur][(wn + ni * 16 + lm) * 32 + lk];
        for (int mi = 0; mi < 2; ++mi)
            for (int ni = 0; ni < 4; ++ni)
                acc[mi][ni] = __builtin_amdgcn_mfma_f32_16x16x32_bf16(
                    af[mi], bfr[ni], acc[mi][ni], 0, 0, 0);
        __syncthreads();
    }

    int store_f32 = (f == 0);
    int cn = lane & 15, cr = (lane >> 4) * 4;
    for (int ni = 0; ni < 4; ++ni) {
        int gn = n0 + wn + ni * 16 + cn;
        float bb = f ? b2f(((const u16*)bias)[gn]) : ((const float*)bias)[gn];
        for (int mi = 0; mi < 2; ++mi)
            for (int r = 0; r < 4; ++r) {
                int gm = m0 + wm + mi * 16 + cr + r;
                float v = acc[mi][ni][r] + bb;
                size_t o = (size_t)gm * N + gn;
                if (store_f32) Cf[o] = v;
                else           Cb[o] = f2b(v);
            }
    }
}

// ---- MFMA sparse attention (R8-proven attn4: fixed bounds, head-major) ----
#define VP 264
#define PP 264
__global__ __launch_bounds__(256) void k_attn4(const u16* __restrict__ QKV,
                                               u16* __restrict__ AO) {
    int bx = blockIdx.x, h = blockIdx.y, b = blockIdx.z;
    int qb = bx >> 1, sb = bx & 1;
    int t = threadIdx.x, lane = t & 63, wave = t >> 6;
    int lm = lane & 15, q4 = lane >> 4;
    int nstr = qb << 3;
    int nk = nstr + (sb << 6) + 64;     // <= 248
    int r0 = (qb << 7) + (sb << 6);

    __shared__ char smem[79872];
    u16* Vts = (u16*)smem;                       // 64 x 264
    u16* Qs  = (u16*)(smem + 33792);             // 64 x 72
    u16* Ks  = (u16*)(smem + 33792 + 9216);      // 256 x 72
    u16* Ps  = (u16*)(smem + 33792);             // aliases Qs+Ks

    int hm = b * 16 + h;
    const u16* qp = QKV + ((size_t)hm * 2048 + r0) * 64;
    const u16* kp = QKV + ((size_t)(32 + hm) * 2048) * 64;
    const u16* vp = QKV + ((size_t)(64 + hm) * 2048) * 64;

    for (int c = t; c < 512; c += 256) {
        int r = c >> 3, d0 = (c & 7) << 3;
        *(uint4*)&Qs[r * 72 + d0] = *(const uint4*)(qp + c * 8);
    }
    uint4 zz = {0u, 0u, 0u, 0u};
    for (int c = t; c < 2048; c += 256) {
        int i = c >> 3, d0 = (c & 7) << 3;
        uint4 kv = zz;
        if (i < nk) {
            int key = (i < nstr) ? (((i >> 3) << 7) + 120 + (i & 7))
                                 : ((qb << 7) + (i - nstr));
            kv = *(const uint4*)(kp + key * 64 + d0);
        }
        *(uint4*)&Ks[i * 72 + d0] = kv;
    }
    {
        int i0 = (t & 31) * 8, d0 = (t >> 5) * 8;
        u16 m8[8][8];
        for (int r = 0; r < 8; ++r) {
            int i = i0 + r;
            uint4 vv = zz;
            if (i < nk) {
                int key = (i < nstr) ? (((i >> 3) << 7) + 120 + (i & 7))
                                     : ((qb << 7) + (i - nstr));
                vv = *(const uint4*)(vp + key * 64 + d0);
            }
            *(uint4*)m8[r] = vv;
        }
        for (int j = 0; j < 8; ++j) {
            u16 o[8];
            for (int r = 0; r < 8; ++r) o[r] = m8[r][j];
            *(uint4*)&Vts[(d0 + j) * VP + i0] = *(uint4*)o;
        }
    }
    __syncthreads();

    f32x4 acc[16];
    f32x4 z4 = {0.f, 0.f, 0.f, 0.f};
    for (int ni = 0; ni < 16; ++ni) acc[ni] = z4;
    s16x8 af0 = *(const s16x8*)&Qs[(wave * 16 + lm) * 72 + q4 * 8];
    s16x8 af1 = *(const s16x8*)&Qs[(wave * 16 + lm) * 72 + 32 + q4 * 8];
    for (int ni = 0; ni < 16; ++ni) {
        s16x8 bf0 = *(const s16x8*)&Ks[(ni * 16 + lm) * 72 + q4 * 8];
        s16x8 bf1 = *(const s16x8*)&Ks[(ni * 16 + lm) * 72 + 32 + q4 * 8];
        acc[ni] = __builtin_amdgcn_mfma_f32_16x16x32_bf16(af0, bf0, acc[ni], 0, 0, 0);
        acc[ni] = __builtin_amdgcn_mfma_f32_16x16x32_bf16(af1, bf1, acc[ni], 0, 0, 0);
    }
    __syncthreads();

    float mx[4] = {-3e38f, -3e38f, -3e38f, -3e38f};
    for (int ni = 0; ni < 16; ++ni) {
        int i = ni * 16 + lm;
        for (int reg = 0; reg < 4; ++reg) {
            int rl = (sb << 6) + wave * 16 + q4 * 4 + reg;
            bool valid = (i < nstr) || ((i - nstr) <= rl);
            float v = valid ? acc[ni][reg] * 0.125f : -3e38f;
            acc[ni][reg] = v;
            mx[reg] = fmaxf(mx[reg], v);
        }
    }
    for (int reg = 0; reg < 4; ++reg)
        for (int off = 1; off < 16; off <<= 1)
            mx[reg] = fmaxf(mx[reg], __shfl_xor(mx[reg], off, 64));
    float sm[4] = {0.f, 0.f, 0.f, 0.f};
    for (int ni = 0; ni < 16; ++ni)
        for (int reg = 0; reg < 4; ++reg) {
            float e = __expf(acc[ni][reg] - mx[reg]);
            acc[ni][reg] = e;
            sm[reg] += e;
        }
    for (int reg = 0; reg < 4; ++reg)
        for (int off = 1; off < 16; off <<= 1)
            sm[reg] += __shfl_xor(sm[reg], off, 64);
    float inv[4];
    for (int reg = 0; reg < 4; ++reg) inv[reg] = 1.f / sm[reg];

    for (int ni = 0; ni < 16; ++ni) {
        int i = ni * 16 + lm;
        for (int reg = 0; reg < 4; ++reg)
            Ps[(wave * 16 + q4 * 4 + reg) * PP + i] = f2b(acc[ni][reg]);
    }
    __syncthreads();

    f32x4 acc2[4];
    for (int ni2 = 0; ni2 < 4; ++ni2) acc2[ni2] = z4;
    for (int k0 = 0; k0 < 256; k0 += 32) {
        s16x8 pf = *(const s16x8*)&Ps[(wave * 16 + lm) * PP + k0 + q4 * 8];
        for (int ni2 = 0; ni2 < 4; ++ni2) {
            s16x8 vf = *(const s16x8*)&Vts[(ni2 * 16 + lm) * VP + k0 + q4 * 8];
            acc2[ni2] = __builtin_amdgcn_mfma_f32_16x16x32_bf16(pf, vf, acc2[ni2], 0, 0, 0);
        }
    }
    int srow = r0 + wave * 16 + q4 * 4;
    for (int ni2 = 0; ni2 < 4; ++ni2)
        for (int reg = 0; reg < 4; ++reg) {
            size_t o = ((size_t)(b * SDIM + srow + reg)) * EDIM + h * 64 + ni2 * 16 + lm;
            AO[o] = f2b(acc2[ni2][reg] * inv[reg]);
        }
}

extern "C" void kernel_launch(void* const* d_in, const int* in_sizes, int n_in,
                              void* d_out, int out_size, void* d_ws, size_t ws_size,
                              hipStream_t stream) {
    const void* X  = d_in[0];
    const void* Wa = d_in[1];
    const void* ba = d_in[2];
    const void* Wp = d_in[3];
    const void* bp = d_in[4];

    char* w = (char*)d_ws;
    u16* Xb   = (u16*)(w);
    u16* WtA  = (u16*)(w + 8388608);
    u16* WtP  = (u16*)(w + 14680064);
    u16* QKVh = (u16*)(w + 16777216);
    u16* AO   = (u16*)(w + 41943040);

    k_prep<<<dim3(48, 16, 3), 256, 0, stream>>>(X, Wa, Wp, Xb, WtA, WtP);
    k_gemm1<<<dim3(24, 32), 256, 0, stream>>>((const u16*)X, Xb, WtA, ba, QKVh);
    k_attn4<<<dim3(32, 16, 2), 256, 0, stream>>>(QKVh, AO);
    k_gemm2<<<dim3(8, 64), 256, 0, stream>>>((const u16*)X, AO, WtP, bp,
                                             (u16*)d_out, (float*)d_out);
}